// Round 2
// baseline (301.697 us; speedup 1.0000x reference)
//
#include <hip/hip_runtime.h>
#include <math.h>
#include <stdint.h>

#define B_    2
#define T_    2048
#define C_    2048
#define NH_   16
#define G_    4
#define HS_   128
#define WIN_  512
#define NQKV_ 3072
#define M_    4096
#define SCALE_ 0.08838834764831845f

typedef __attribute__((ext_vector_type(8))) __bf16 bf16x8;
typedef __attribute__((ext_vector_type(4))) float f32x4;
typedef unsigned short u16;

static __device__ __forceinline__ u16 f2bf(float f) {
  union { float f; unsigned u; } v; v.f = f;
  unsigned r = v.u + 0x7fffu + ((v.u >> 16) & 1u);
  return (u16)(r >> 16);
}
static __device__ __forceinline__ float bf2f(u16 h) {
  union { unsigned u; float f; } v; v.u = ((unsigned)h) << 16; return v.f;
}
static __device__ __forceinline__ bf16x8 ldg8(const u16* p) {
  return *(const bf16x8*)(const void*)p;
}

// ---------------- x fp32 -> bf16 ----------------
__global__ void cvt_bf16(const float* __restrict__ in, u16* __restrict__ out) {
  int i = blockIdx.x * 256 + threadIdx.x;
  float4 v = ((const float4*)in)[i];
  ushort4 o;
  o.x = f2bf(v.x); o.y = f2bf(v.y); o.z = f2bf(v.z); o.w = f2bf(v.w);
  ((ushort4*)out)[i] = o;
}

// ---------------- transpose fp32 (R x C) -> bf16 (C x R) ----------------
__global__ void transpose_cvt(const float* __restrict__ in, u16* __restrict__ out,
                              int R, int Ccols) {
  __shared__ float tile[32][33];
  int c0 = blockIdx.x * 32, r0 = blockIdx.y * 32;
  int tx = threadIdx.x & 31, ty = threadIdx.x >> 5;  // ty 0..7
#pragma unroll
  for (int i = 0; i < 32; i += 8)
    tile[ty + i][tx] = in[(size_t)(r0 + ty + i) * Ccols + c0 + tx];
  __syncthreads();
#pragma unroll
  for (int i = 0; i < 32; i += 8)
    out[(size_t)(c0 + ty + i) * R + r0 + tx] = f2bf(tile[tx][ty + i]);
}

// ---------------- transpose bf16 v (per b: T x 512 -> 512 x T) ----------------
__global__ void transpose_v16(const u16* __restrict__ in, u16* __restrict__ out) {
  __shared__ u16 tile[32][33];
  int b = blockIdx.z;
  int c0 = blockIdx.x * 32, t0 = blockIdx.y * 32;
  int tx = threadIdx.x & 31, ty = threadIdx.x >> 5;
  const u16* src = in + (size_t)b * T_ * (G_*HS_);
  u16* dst = out + (size_t)b * (G_*HS_) * T_;
#pragma unroll
  for (int i = 0; i < 32; i += 8)
    tile[ty + i][tx] = src[(size_t)(t0 + ty + i) * (G_*HS_) + c0 + tx];
  __syncthreads();
#pragma unroll
  for (int i = 0; i < 32; i += 8)
    dst[(size_t)(c0 + ty + i) * T_ + t0 + tx] = tile[tx][ty + i];
}

// ---------------- GEMM: C[M][N] = A[M][K] * Bt[N][K]^T  (bf16 MFMA, m97-style) ----
template<int N, int K, int OUTBF>
__global__ __launch_bounds__(256)
void gemm_bt(const u16* __restrict__ A, const u16* __restrict__ Bt,
             u16* __restrict__ Cb, float* __restrict__ Cf) {
  __shared__ u16 lA[128 * 32];
  __shared__ u16 lB[128 * 32];
  const int m0 = blockIdx.x * 128;
  const int n0 = blockIdx.y * 128;
  const int lane = threadIdx.x & 63;
  const int wave = threadIdx.x >> 6;
  const int wr = (wave >> 1) * 64, wc = (wave & 1) * 64;
  const int fr = lane & 15, fk = (lane >> 4) * 8;
  const int srow = lane >> 2;
  const int scol = (lane & 3) * 8;
  f32x4 acc[4][4] = {};
  for (int k0 = 0; k0 < K; k0 += 32) {
#pragma unroll
    for (int c = 0; c < 2; ++c) {
      int chunk = wave * 2 + c;
      int row = chunk * 16 + srow;
      __builtin_amdgcn_global_load_lds(
          (__attribute__((address_space(1))) void*)(A + (size_t)(m0 + row) * K + k0 + scol),
          (__attribute__((address_space(3))) void*)(lA + chunk * 512), 16, 0, 0);
      __builtin_amdgcn_global_load_lds(
          (__attribute__((address_space(1))) void*)(Bt + (size_t)(n0 + row) * K + k0 + scol),
          (__attribute__((address_space(3))) void*)(lB + chunk * 512), 16, 0, 0);
    }
    __syncthreads();
    bf16x8 af[4], bb[4];
#pragma unroll
    for (int i = 0; i < 4; ++i) {
      af[i] = ldg8(lA + (wr + i * 16 + fr) * 32 + fk);
      bb[i] = ldg8(lB + (wc + i * 16 + fr) * 32 + fk);
    }
#pragma unroll
    for (int i = 0; i < 4; ++i)
#pragma unroll
      for (int j = 0; j < 4; ++j)
        acc[i][j] = __builtin_amdgcn_mfma_f32_16x16x32_bf16(af[i], bb[j], acc[i][j], 0, 0, 0);
    __syncthreads();
  }
  const int orow = m0 + wr + (lane >> 4) * 4;
  const int ocol = n0 + wc + fr;
#pragma unroll
  for (int i = 0; i < 4; ++i)
#pragma unroll
    for (int j = 0; j < 4; ++j)
#pragma unroll
      for (int jj = 0; jj < 4; ++jj) {
        int r = orow + i * 16 + jj, cc = ocol + j * 16;
        if (OUTBF) Cb[(size_t)r * N + cc] = f2bf(acc[i][j][jj]);
        else       Cf[(size_t)r * N + cc] = acc[i][j][jj];
      }
}

// ---------------- conv(K=4) + SiLU helper ----------------
static __device__ __forceinline__ float conv_silu(const u16* __restrict__ qkv, int bt, int t,
                                                  int col, const float* __restrict__ w4) {
  float4 w = *(const float4*)w4;
  const u16* p = qkv + (size_t)bt * NQKV_ + col;
  float acc;
  if (t >= 3) {
    acc = w.x * bf2f(p[-3 * NQKV_]) + w.y * bf2f(p[-2 * NQKV_]) +
          w.z * bf2f(p[-1 * NQKV_]) + w.w * bf2f(p[0]);
  } else {
    acc = w.w * bf2f(p[0]);
    if (t >= 1) acc += w.z * bf2f(p[-1 * NQKV_]);
    if (t >= 2) acc += w.y * bf2f(p[-2 * NQKV_]);
  }
  return acc / (1.f + __expf(-acc));
}

// ---------------- q: conv + silu + rope (+fold SCALE) ----------------
__global__ void conv_rope_q(const u16* __restrict__ qkv, const float* __restrict__ w,
                            const float* __restrict__ cosT, const float* __restrict__ sinT,
                            u16* __restrict__ qout) {
  int part = blockIdx.x & 3;
  int bt = blockIdx.x >> 2;
  int t = bt & (T_ - 1);
  int pidx = part * 256 + threadIdx.x;
  int h = pidx >> 6, d = pidx & 63;
  int g = h >> 2, s = h & 3;
  int col = (g * 6 + s) * 128 + d;
  float a1 = conv_silu(qkv, bt, t, col,      w + (size_t)(h * 128 + d) * 4);
  float a2 = conv_silu(qkv, bt, t, col + 64, w + (size_t)(h * 128 + d + 64) * 4);
  float c = cosT[t * 64 + d], sn = sinT[t * 64 + d];
  u16* dst = qout + ((size_t)bt * NH_ + h) * HS_ + d;
  dst[0]  = f2bf((a1 * c - a2 * sn) * SCALE_);
  dst[64] = f2bf((a1 * sn + a2 * c) * SCALE_);
}

// ---------------- k: conv+silu+rope ; v: conv+silu ----------------
__global__ void conv_kv(const u16* __restrict__ qkv, const float* __restrict__ kw,
                        const float* __restrict__ vw, const float* __restrict__ cosT,
                        const float* __restrict__ sinT,
                        u16* __restrict__ kout, u16* __restrict__ vtmp) {
  int bt = blockIdx.x;
  int t = bt & (T_ - 1);
  int g = threadIdx.x >> 6, d = threadIdx.x & 63;
  if (blockIdx.y == 0) {
    int col = (g * 6 + 4) * 128 + d;
    float a1 = conv_silu(qkv, bt, t, col,      kw + (size_t)(g * 128 + d) * 4);
    float a2 = conv_silu(qkv, bt, t, col + 64, kw + (size_t)(g * 128 + d + 64) * 4);
    float c = cosT[t * 64 + d], sn = sinT[t * 64 + d];
    u16* dst = kout + ((size_t)bt * G_ + g) * HS_ + d;
    dst[0]  = f2bf(a1 * c - a2 * sn);
    dst[64] = f2bf(a1 * sn + a2 * c);
  } else {
    int col = (g * 6 + 5) * 128 + d;
    float a1 = conv_silu(qkv, bt, t, col,      vw + (size_t)(g * 128 + d) * 4);
    float a2 = conv_silu(qkv, bt, t, col + 64, vw + (size_t)(g * 128 + d + 64) * 4);
    u16* dst = vtmp + ((size_t)bt * G_ + g) * HS_ + d;
    dst[0]  = f2bf(a1);
    dst[64] = f2bf(a2);
  }
}

// ---------------- sliding-window GQA flash attention (v2) ----------------
// swapped QK^T: lane = one query row (q = lane&15); KVBLK=64; per-lane softmax;
// P via XOR-swizzled per-wave LDS tile; O accumulated in standard orientation.
__global__ __launch_bounds__(256, 4)
void attn_swin(const u16* __restrict__ qbf, const u16* __restrict__ kbf,
               const u16* __restrict__ vt, u16* __restrict__ ybf) {
  __shared__ u16 plds[4][16 * 64];   // per-wave 2KB P tile [q=16][s=64], swizzled
  const int lane = threadIdx.x & 63;
  const int wave = threadIdx.x >> 6;
  const int gidx = blockIdx.x * 4 + wave;
  const int t0 = (gidx & 127) << 4;
  const int h  = (gidx >> 7) & 15;
  const int b  = gidx >> 11;
  const int g  = h >> 2;
  const int fr = lane & 15;          // query index within tile (fragment row/col)
  const int hi = lane >> 4;          // 0..3
  const int fko = hi * 8;            // k-offset within a 32-wide K chunk
  const int qr = t0 + fr;            // this lane's query row
  u16* pl = plds[wave];
  const int swz = (fr & 7) << 4;     // byte XOR swizzle for row fr

  // Q fragment (op2 of swapped QK; also reused layout-identical as op1 elsewhere)
  bf16x8 qf[4];
  {
    const u16* qb = qbf + ((size_t)((b * T_ + t0 + fr) * NH_ + h)) * HS_ + fko;
#pragma unroll
    for (int kc = 0; kc < 4; ++kc) qf[kc] = ldg8(qb + kc * 32);
  }

  f32x4 acc_o[8];
#pragma unroll
  for (int n = 0; n < 8; ++n) acc_o[n] = (f32x4){0.f, 0.f, 0.f, 0.f};
  float m_r = -1e30f, l_r = 0.f;

  int sbeg = t0 - (WIN_ - 1); if (sbeg < 0) sbeg = 0; sbeg &= ~63;

  for (int s0 = sbeg; s0 <= t0 + 15; s0 += 64) {
    // ---- QK^T (swapped): st[c] holds S^T[s = s0+c*16+hi*4+j][q = fr] ----
    f32x4 st[4];
#pragma unroll
    for (int c = 0; c < 4; ++c) {
      st[c] = (f32x4){0.f, 0.f, 0.f, 0.f};
      if (s0 + c * 16 < T_) {
        const u16* kb = kbf + ((size_t)((b * T_ + s0 + c * 16 + fr) * G_ + g)) * HS_ + fko;
#pragma unroll
        for (int kc = 0; kc < 4; ++kc)
          st[c] = __builtin_amdgcn_mfma_f32_16x16x32_bf16(ldg8(kb + kc * 32), qf[kc], st[c], 0, 0, 0);
      }
    }
    // ---- mask + per-lane max ----
    float tmax = -1e30f;
#pragma unroll
    for (int c = 0; c < 4; ++c)
#pragma unroll
      for (int j = 0; j < 4; ++j) {
        int key = s0 + c * 16 + hi * 4 + j;
        int dlt = qr - key;
        float x = (dlt >= 0 && dlt < WIN_) ? st[c][j] : -1e30f;
        st[c][j] = x;
        tmax = fmaxf(tmax, x);
      }
    tmax = fmaxf(tmax, __shfl_xor(tmax, 16, 64));
    tmax = fmaxf(tmax, __shfl_xor(tmax, 32, 64));
    float mn  = fmaxf(m_r, tmax);
    float fac = __expf(m_r - mn);
    m_r = mn;
    // ---- exp + P write (swizzled) + per-lane sum ----
    float ps = 0.f;
#pragma unroll
    for (int c = 0; c < 4; ++c) {
      union { ushort4 u4; __bf16 hh[4]; } pk;
#pragma unroll
      for (int j = 0; j < 4; ++j) {
        float p = (st[c][j] > -1e29f) ? __expf(st[c][j] - mn) : 0.f;
        ps += p;
        pk.hh[j] = (__bf16)p;
      }
      *(ushort4*)((char*)pl + (fr * 128 + ((c * 32 + hi * 8) ^ swz))) = pk.u4;
    }
    ps += __shfl_xor(ps, 16, 64);
    ps += __shfl_xor(ps, 32, 64);
    l_r = l_r * fac + ps;
    // ---- rescale O (fac is per-q scalar; redistribute to acc rows) ----
    float fq0 = __shfl(fac, hi * 4 + 0, 64);
    float fq1 = __shfl(fac, hi * 4 + 1, 64);
    float fq2 = __shfl(fac, hi * 4 + 2, 64);
    float fq3 = __shfl(fac, hi * 4 + 3, 64);
#pragma unroll
    for (int n = 0; n < 8; ++n) {
      acc_o[n][0] *= fq0; acc_o[n][1] *= fq1;
      acc_o[n][2] *= fq2; acc_o[n][3] *= fq3;
    }
    // ---- PV: O[q][d] += P[q][s] * V[s][d] ----
#pragma unroll
    for (int ch = 0; ch < 2; ++ch) {
      if (s0 + ch * 32 < T_) {
        bf16x8 pa = *(const bf16x8*)((const char*)pl + (fr * 128 + ((ch * 64 + hi * 16) ^ swz)));
        const u16* vb = vt + ((size_t)(b * (G_*HS_) + g * HS_ + fr)) * T_ + s0 + ch * 32 + fko;
#pragma unroll
        for (int n = 0; n < 8; ++n)
          acc_o[n] = __builtin_amdgcn_mfma_f32_16x16x32_bf16(pa, ldg8(vb + (size_t)(n * 16) * T_), acc_o[n], 0, 0, 0);
      }
    }
  }
  // ---- epilogue ----
  float inv = 1.f / l_r;
  float iq0 = __shfl(inv, hi * 4 + 0, 64);
  float iq1 = __shfl(inv, hi * 4 + 1, 64);
  float iq2 = __shfl(inv, hi * 4 + 2, 64);
  float iq3 = __shfl(inv, hi * 4 + 3, 64);
  float iq[4] = {iq0, iq1, iq2, iq3};
#pragma unroll
  for (int n = 0; n < 8; ++n)
#pragma unroll
    for (int jj = 0; jj < 4; ++jj) {
      int t = t0 + hi * 4 + jj;
      ybf[((size_t)(b * T_ + t)) * (NH_*HS_) + h * HS_ + n * 16 + fr] = f2bf(acc_o[n][jj] * iq[jj]);
    }
}

extern "C" void kernel_launch(void* const* d_in, const int* in_sizes, int n_in,
                              void* d_out, int out_size, void* d_ws, size_t ws_size,
                              hipStream_t stream) {
  (void)in_sizes; (void)n_in; (void)out_size;
  const float* x     = (const float*)d_in[0];
  const float* Wqkv  = (const float*)d_in[1];
  const float* Wproj = (const float*)d_in[2];
  const float* qw    = (const float*)d_in[3];
  const float* kw    = (const float*)d_in[4];
  const float* vw    = (const float*)d_in[5];
  const float* cosT  = (const float*)d_in[6];
  const float* sinT  = (const float*)d_in[7];
  float* out = (float*)d_out;
  char* ws = (char*)d_ws;

  // workspace layout (bytes)
  u16* x_bf    = (u16*)(ws + 0);          // 4096*2048*2   = 16,777,216
  u16* wqkv_t  = (u16*)(ws + 16777216);   // 3072*2048*2   = 12,582,912
  u16* wproj_t = (u16*)(ws + 29360128);   // 2048*2048*2   =  8,388,608
  u16* qkv_bf  = (u16*)(ws + 37748736);   // 4096*3072*2   = 25,165,824
  u16* q_bf    = (u16*)(ws + 62914560);   // 2*2048*16*128*2 = 16,777,216
  u16* k_bf    = (u16*)(ws + 79691776);   // 2*2048*4*128*2  =  4,194,304
  u16* v_tmp   = (u16*)(ws + 83886080);   //                  4,194,304
  u16* v_t     = (u16*)(ws + 88080384);   //                  4,194,304
  u16* y_bf    = (u16*)(ws + 92274688);   // 4096*2048*2   = 16,777,216
  if (ws_size < (size_t)109051904) return;

  cvt_bf16<<<8192, 256, 0, stream>>>(x, x_bf);
  transpose_cvt<<<dim3(96, 64), 256, 0, stream>>>(Wqkv, wqkv_t, 2048, 3072);
  transpose_cvt<<<dim3(64, 64), 256, 0, stream>>>(Wproj, wproj_t, 2048, 2048);
  gemm_bt<3072, 2048, 1><<<dim3(32, 24), 256, 0, stream>>>(x_bf, wqkv_t, qkv_bf, nullptr);
  conv_rope_q<<<16384, 256, 0, stream>>>(qkv_bf, qw, cosT, sinT, q_bf);
  conv_kv<<<dim3(4096, 2), 256, 0, stream>>>(qkv_bf, kw, vw, cosT, sinT, k_bf, v_tmp);
  transpose_v16<<<dim3(16, 64, 2), 256, 0, stream>>>(v_tmp, v_t);
  attn_swin<<<1024, 256, 0, stream>>>(q_bf, k_bf, v_t, y_bf);
  gemm_bt<2048, 2048, 0><<<dim3(32, 16), 256, 0, stream>>>(y_bf, wproj_t, nullptr, out);
}

// Round 3
// 213.792 us; speedup vs baseline: 1.4112x; 1.4112x over previous
//
#include <hip/hip_runtime.h>
#include <math.h>
#include <stdint.h>

#define B_    2
#define T_    2048
#define C_    2048
#define NH_   16
#define G_    4
#define HS_   128
#define WIN_  512
#define NQKV_ 3072
#define M_    4096
#define SCALE_ 0.08838834764831845f

typedef __attribute__((ext_vector_type(8))) __bf16 bf16x8;
typedef __attribute__((ext_vector_type(4))) float f32x4;
typedef unsigned short u16;

static __device__ __forceinline__ u16 f2bf(float f) {
  union { float f; unsigned u; } v; v.f = f;
  unsigned r = v.u + 0x7fffu + ((v.u >> 16) & 1u);
  return (u16)(r >> 16);
}
static __device__ __forceinline__ float bf2f(u16 h) {
  union { unsigned u; float f; } v; v.u = ((unsigned)h) << 16; return v.f;
}
static __device__ __forceinline__ bf16x8 ldg8(const u16* p) {
  return *(const bf16x8*)(const void*)p;
}

// ---------------- x fp32 -> bf16 ----------------
__global__ void cvt_bf16(const float* __restrict__ in, u16* __restrict__ out) {
  int i = blockIdx.x * 256 + threadIdx.x;
  float4 v = ((const float4*)in)[i];
  ushort4 o;
  o.x = f2bf(v.x); o.y = f2bf(v.y); o.z = f2bf(v.z); o.w = f2bf(v.w);
  ((ushort4*)out)[i] = o;
}

// ---------------- transpose fp32 (R x C) -> bf16 (C x R) ----------------
__global__ void transpose_cvt(const float* __restrict__ in, u16* __restrict__ out,
                              int R, int Ccols) {
  __shared__ float tile[32][33];
  int c0 = blockIdx.x * 32, r0 = blockIdx.y * 32;
  int tx = threadIdx.x & 31, ty = threadIdx.x >> 5;  // ty 0..7
#pragma unroll
  for (int i = 0; i < 32; i += 8)
    tile[ty + i][tx] = in[(size_t)(r0 + ty + i) * Ccols + c0 + tx];
  __syncthreads();
#pragma unroll
  for (int i = 0; i < 32; i += 8)
    out[(size_t)(c0 + ty + i) * R + r0 + tx] = f2bf(tile[tx][ty + i]);
}

// ---------------- transpose bf16 v (per b: T x 512 -> 512 x T) ----------------
__global__ void transpose_v16(const u16* __restrict__ in, u16* __restrict__ out) {
  __shared__ u16 tile[32][33];
  int b = blockIdx.z;
  int c0 = blockIdx.x * 32, t0 = blockIdx.y * 32;
  int tx = threadIdx.x & 31, ty = threadIdx.x >> 5;
  const u16* src = in + (size_t)b * T_ * (G_*HS_);
  u16* dst = out + (size_t)b * (G_*HS_) * T_;
#pragma unroll
  for (int i = 0; i < 32; i += 8)
    tile[ty + i][tx] = src[(size_t)(t0 + ty + i) * (G_*HS_) + c0 + tx];
  __syncthreads();
#pragma unroll
  for (int i = 0; i < 32; i += 8)
    dst[(size_t)(c0 + ty + i) * T_ + t0 + tx] = tile[tx][ty + i];
}

// ---------------- GEMM: C[M][N] = A[M][K] * Bt[N][K]^T  (bf16 MFMA, m97-style) ----
template<int N, int K, int OUTBF>
__global__ __launch_bounds__(256)
void gemm_bt(const u16* __restrict__ A, const u16* __restrict__ Bt,
             u16* __restrict__ Cb, float* __restrict__ Cf) {
  __shared__ u16 lA[128 * 32];
  __shared__ u16 lB[128 * 32];
  const int m0 = blockIdx.x * 128;
  const int n0 = blockIdx.y * 128;
  const int lane = threadIdx.x & 63;
  const int wave = threadIdx.x >> 6;
  const int wr = (wave >> 1) * 64, wc = (wave & 1) * 64;
  const int fr = lane & 15, fk = (lane >> 4) * 8;
  const int srow = lane >> 2;
  const int scol = (lane & 3) * 8;
  f32x4 acc[4][4] = {};
  for (int k0 = 0; k0 < K; k0 += 32) {
#pragma unroll
    for (int c = 0; c < 2; ++c) {
      int chunk = wave * 2 + c;
      int row = chunk * 16 + srow;
      __builtin_amdgcn_global_load_lds(
          (__attribute__((address_space(1))) void*)(A + (size_t)(m0 + row) * K + k0 + scol),
          (__attribute__((address_space(3))) void*)(lA + chunk * 512), 16, 0, 0);
      __builtin_amdgcn_global_load_lds(
          (__attribute__((address_space(1))) void*)(Bt + (size_t)(n0 + row) * K + k0 + scol),
          (__attribute__((address_space(3))) void*)(lB + chunk * 512), 16, 0, 0);
    }
    __syncthreads();
    bf16x8 af[4], bb[4];
#pragma unroll
    for (int i = 0; i < 4; ++i) {
      af[i] = ldg8(lA + (wr + i * 16 + fr) * 32 + fk);
      bb[i] = ldg8(lB + (wc + i * 16 + fr) * 32 + fk);
    }
#pragma unroll
    for (int i = 0; i < 4; ++i)
#pragma unroll
      for (int j = 0; j < 4; ++j)
        acc[i][j] = __builtin_amdgcn_mfma_f32_16x16x32_bf16(af[i], bb[j], acc[i][j], 0, 0, 0);
    __syncthreads();
  }
  const int orow = m0 + wr + (lane >> 4) * 4;
  const int ocol = n0 + wc + fr;
#pragma unroll
  for (int i = 0; i < 4; ++i)
#pragma unroll
    for (int j = 0; j < 4; ++j)
#pragma unroll
      for (int jj = 0; jj < 4; ++jj) {
        int r = orow + i * 16 + jj, cc = ocol + j * 16;
        if (OUTBF) Cb[(size_t)r * N + cc] = f2bf(acc[i][j][jj]);
        else       Cf[(size_t)r * N + cc] = acc[i][j][jj];
      }
}

// ---------------- conv(K=4) + SiLU helper ----------------
static __device__ __forceinline__ float conv_silu(const u16* __restrict__ qkv, int bt, int t,
                                                  int col, const float* __restrict__ w4) {
  float4 w = *(const float4*)w4;
  const u16* p = qkv + (size_t)bt * NQKV_ + col;
  float acc;
  if (t >= 3) {
    acc = w.x * bf2f(p[-3 * NQKV_]) + w.y * bf2f(p[-2 * NQKV_]) +
          w.z * bf2f(p[-1 * NQKV_]) + w.w * bf2f(p[0]);
  } else {
    acc = w.w * bf2f(p[0]);
    if (t >= 1) acc += w.z * bf2f(p[-1 * NQKV_]);
    if (t >= 2) acc += w.y * bf2f(p[-2 * NQKV_]);
  }
  return acc / (1.f + __expf(-acc));
}

// ---------------- q: conv + silu + rope (+fold SCALE) ----------------
__global__ void conv_rope_q(const u16* __restrict__ qkv, const float* __restrict__ w,
                            const float* __restrict__ cosT, const float* __restrict__ sinT,
                            u16* __restrict__ qout) {
  int part = blockIdx.x & 3;
  int bt = blockIdx.x >> 2;
  int t = bt & (T_ - 1);
  int pidx = part * 256 + threadIdx.x;
  int h = pidx >> 6, d = pidx & 63;
  int g = h >> 2, s = h & 3;
  int col = (g * 6 + s) * 128 + d;
  float a1 = conv_silu(qkv, bt, t, col,      w + (size_t)(h * 128 + d) * 4);
  float a2 = conv_silu(qkv, bt, t, col + 64, w + (size_t)(h * 128 + d + 64) * 4);
  float c = cosT[t * 64 + d], sn = sinT[t * 64 + d];
  u16* dst = qout + ((size_t)bt * NH_ + h) * HS_ + d;
  dst[0]  = f2bf((a1 * c - a2 * sn) * SCALE_);
  dst[64] = f2bf((a1 * sn + a2 * c) * SCALE_);
}

// ---------------- k: conv+silu+rope ; v: conv+silu ----------------
__global__ void conv_kv(const u16* __restrict__ qkv, const float* __restrict__ kw,
                        const float* __restrict__ vw, const float* __restrict__ cosT,
                        const float* __restrict__ sinT,
                        u16* __restrict__ kout, u16* __restrict__ vtmp) {
  int bt = blockIdx.x;
  int t = bt & (T_ - 1);
  int g = threadIdx.x >> 6, d = threadIdx.x & 63;
  if (blockIdx.y == 0) {
    int col = (g * 6 + 4) * 128 + d;
    float a1 = conv_silu(qkv, bt, t, col,      kw + (size_t)(g * 128 + d) * 4);
    float a2 = conv_silu(qkv, bt, t, col + 64, kw + (size_t)(g * 128 + d + 64) * 4);
    float c = cosT[t * 64 + d], sn = sinT[t * 64 + d];
    u16* dst = kout + ((size_t)bt * G_ + g) * HS_ + d;
    dst[0]  = f2bf(a1 * c - a2 * sn);
    dst[64] = f2bf(a1 * sn + a2 * c);
  } else {
    int col = (g * 6 + 5) * 128 + d;
    float a1 = conv_silu(qkv, bt, t, col,      vw + (size_t)(g * 128 + d) * 4);
    float a2 = conv_silu(qkv, bt, t, col + 64, vw + (size_t)(g * 128 + d + 64) * 4);
    u16* dst = vtmp + ((size_t)bt * G_ + g) * HS_ + d;
    dst[0]  = f2bf(a1);
    dst[64] = f2bf(a2);
  }
}

// ---------------- sliding-window GQA flash attention (v3) ----------------
// block = 64 queries of one (b,h); 4 waves x 16q. K/V 64-key tiles staged
// cooperatively into double-buffered, XOR-swizzled LDS via global_load_lds
// (swizzle applied on global source; linear LDS dest). 2-phase pipeline:
// stage(t+1) issued before compute(t), one barrier per tile.
__global__ __launch_bounds__(256, 2)
void attn_swin(const u16* __restrict__ qbf, const u16* __restrict__ kbf,
               const u16* __restrict__ vt, u16* __restrict__ ybf) {
  __shared__ __align__(16) char kls[2][16384];  // [64 s][256 B] swizzled
  __shared__ __align__(16) char vls[2][16384];  // [128 d][128 B] swizzled
  __shared__ __align__(16) char pls[4][2048];   // per-wave P [16 q][128 B] swizzled
  const int lane = threadIdx.x & 63;
  const int wave = threadIdx.x >> 6;
  const int btile = blockIdx.x & 31;
  const int h  = (blockIdx.x >> 5) & 15;
  const int b  = blockIdx.x >> 9;
  const int g  = h >> 2;
  const int t0b = btile << 6;
  const int t0w = t0b + wave * 16;
  const int fr = lane & 15;
  const int hi = lane >> 4;
  const int fko = hi * 8;
  const int qr = t0w + fr;
  char* pl = pls[wave];
  const int swz = (fr & 7) << 4;

  // per-lane staging geometry (4 K-insts + 4 V-insts per wave)
  const int krow_l = (lane >> 4);            // +4*i
  const int kcb    = (lane & 15) * 16;
  const int vrow_l = (lane >> 3);            // +8*i
  const int vcb    = (lane & 7) * 16;

  // Q fragments
  bf16x8 qf[4];
  {
    const u16* qb = qbf + ((size_t)((b * T_ + t0w + fr) * NH_ + h)) * HS_ + fko;
#pragma unroll
    for (int kc = 0; kc < 4; ++kc) qf[kc] = ldg8(qb + kc * 32);
  }

  int sbeg = t0b - (WIN_ - 1); if (sbeg < 0) sbeg = 0; sbeg &= ~63;
  const int nt = (t0b + 64 - sbeg) >> 6;

  const char* kgbase = (const char*)kbf + (((size_t)(b * T_) * G_ + g) * HS_) * 2;
  const char* vgbase = (const char*)vt + ((size_t)(b * (G_*HS_) + g * HS_)) * T_ * 2;

  auto stage = [&](int bufi, int s0) {
    char* kb = kls[bufi]; char* vb = vls[bufi];
#pragma unroll
    for (int c = 0; c < 4; ++c) {
      int i = wave * 4 + c;
      {
        int row = i * 4 + krow_l;
        int scb = kcb ^ ((row & 7) << 4);
        const char* src = kgbase + (size_t)(s0 + row) * (G_*HS_*2) + scb;
        __builtin_amdgcn_global_load_lds(
            (__attribute__((address_space(1))) void*)src,
            (__attribute__((address_space(3))) void*)(kb + i * 1024), 16, 0, 0);
      }
      {
        int row = i * 8 + vrow_l;
        int scb = vcb ^ ((row & 7) << 4);
        const char* src = vgbase + (size_t)row * (T_*2) + (size_t)s0 * 2 + scb;
        __builtin_amdgcn_global_load_lds(
            (__attribute__((address_space(1))) void*)src,
            (__attribute__((address_space(3))) void*)(vb + i * 1024), 16, 0, 0);
      }
    }
  };

  f32x4 acc_o[8];
#pragma unroll
  for (int n = 0; n < 8; ++n) acc_o[n] = (f32x4){0.f, 0.f, 0.f, 0.f};
  float m_r = -1e30f, l_r = 0.f;

  stage(0, sbeg);
  __syncthreads();
  int cur = 0;

  for (int t = 0; t < nt; ++t) {
    int s0 = sbeg + (t << 6);
    if (t + 1 < nt) stage(cur ^ 1, s0 + 64);
    const char* kb = kls[cur];
    const char* vb = vls[cur];

    // ---- QK^T (swapped): st[c] holds S^T[s=s0+c*16+hi*4+j][q=fr] ----
    f32x4 st[4];
    __builtin_amdgcn_s_setprio(1);
#pragma unroll
    for (int c = 0; c < 4; ++c) {
      st[c] = (f32x4){0.f, 0.f, 0.f, 0.f};
      int row = c * 16 + fr;
#pragma unroll
      for (int kc = 0; kc < 4; ++kc) {
        bf16x8 kf = *(const bf16x8*)(kb + row * 256 + ((kc * 64 + hi * 16) ^ swz));
        st[c] = __builtin_amdgcn_mfma_f32_16x16x32_bf16(kf, qf[kc], st[c], 0, 0, 0);
      }
    }
    __builtin_amdgcn_s_setprio(0);

    // ---- mask + per-lane max ----
    float tmax = -1e30f;
#pragma unroll
    for (int c = 0; c < 4; ++c)
#pragma unroll
      for (int j = 0; j < 4; ++j) {
        int key = s0 + c * 16 + hi * 4 + j;
        int dlt = qr - key;
        float x = (dlt >= 0 && dlt < WIN_) ? st[c][j] : -1e30f;
        st[c][j] = x;
        tmax = fmaxf(tmax, x);
      }
    tmax = fmaxf(tmax, __shfl_xor(tmax, 16, 64));
    tmax = fmaxf(tmax, __shfl_xor(tmax, 32, 64));
    float mn  = fmaxf(m_r, tmax);
    float fac = __expf(m_r - mn);
    m_r = mn;

    // ---- exp + P write (swizzled) + per-lane sum ----
    float ps = 0.f;
#pragma unroll
    for (int c = 0; c < 4; ++c) {
      union { ushort4 u4; __bf16 hh[4]; } pk;
#pragma unroll
      for (int j = 0; j < 4; ++j) {
        float p = (st[c][j] > -1e29f) ? __expf(st[c][j] - mn) : 0.f;
        ps += p;
        pk.hh[j] = (__bf16)p;
      }
      *(ushort4*)(pl + fr * 128 + ((c * 32 + hi * 8) ^ swz)) = pk.u4;
    }
    ps += __shfl_xor(ps, 16, 64);
    ps += __shfl_xor(ps, 32, 64);
    l_r = l_r * fac + ps;

    // ---- rescale O ----
    float fq0 = __shfl(fac, hi * 4 + 0, 64);
    float fq1 = __shfl(fac, hi * 4 + 1, 64);
    float fq2 = __shfl(fac, hi * 4 + 2, 64);
    float fq3 = __shfl(fac, hi * 4 + 3, 64);
#pragma unroll
    for (int n = 0; n < 8; ++n) {
      acc_o[n][0] *= fq0; acc_o[n][1] *= fq1;
      acc_o[n][2] *= fq2; acc_o[n][3] *= fq3;
    }

    // ---- PV: O[q][d] += P[q][s] * V[s][d] ----
#pragma unroll
    for (int ch = 0; ch < 2; ++ch) {
      bf16x8 pa = *(const bf16x8*)(pl + fr * 128 + ((ch * 64 + hi * 16) ^ swz));
      __builtin_amdgcn_s_setprio(1);
#pragma unroll
      for (int n = 0; n < 8; ++n) {
        int row = n * 16 + fr;
        bf16x8 vf = *(const bf16x8*)(vb + row * 128 + ((ch * 64 + hi * 16) ^ swz));
        acc_o[n] = __builtin_amdgcn_mfma_f32_16x16x32_bf16(pa, vf, acc_o[n], 0, 0, 0);
      }
      __builtin_amdgcn_s_setprio(0);
    }
    __syncthreads();
    cur ^= 1;
  }

  // ---- epilogue ----
  float inv = 1.f / l_r;
  float iq[4];
#pragma unroll
  for (int j = 0; j < 4; ++j) iq[j] = __shfl(inv, hi * 4 + j, 64);
#pragma unroll
  for (int n = 0; n < 8; ++n)
#pragma unroll
    for (int jj = 0; jj < 4; ++jj) {
      int t = t0w + hi * 4 + jj;
      ybf[((size_t)(b * T_ + t)) * (NH_*HS_) + h * HS_ + n * 16 + fr] = f2bf(acc_o[n][jj] * iq[jj]);
    }
}

extern "C" void kernel_launch(void* const* d_in, const int* in_sizes, int n_in,
                              void* d_out, int out_size, void* d_ws, size_t ws_size,
                              hipStream_t stream) {
  (void)in_sizes; (void)n_in; (void)out_size;
  const float* x     = (const float*)d_in[0];
  const float* Wqkv  = (const float*)d_in[1];
  const float* Wproj = (const float*)d_in[2];
  const float* qw    = (const float*)d_in[3];
  const float* kw    = (const float*)d_in[4];
  const float* vw    = (const float*)d_in[5];
  const float* cosT  = (const float*)d_in[6];
  const float* sinT  = (const float*)d_in[7];
  float* out = (float*)d_out;
  char* ws = (char*)d_ws;

  // workspace layout (bytes)
  u16* x_bf    = (u16*)(ws + 0);          // 4096*2048*2   = 16,777,216
  u16* wqkv_t  = (u16*)(ws + 16777216);   // 3072*2048*2   = 12,582,912
  u16* wproj_t = (u16*)(ws + 29360128);   // 2048*2048*2   =  8,388,608
  u16* qkv_bf  = (u16*)(ws + 37748736);   // 4096*3072*2   = 25,165,824
  u16* q_bf    = (u16*)(ws + 62914560);   // 2*2048*16*128*2 = 16,777,216
  u16* k_bf    = (u16*)(ws + 79691776);   // 2*2048*4*128*2  =  4,194,304
  u16* v_tmp   = (u16*)(ws + 83886080);   //                  4,194,304
  u16* v_t     = (u16*)(ws + 88080384);   //                  4,194,304
  u16* y_bf    = (u16*)(ws + 92274688);   // 4096*2048*2   = 16,777,216
  if (ws_size < (size_t)109051904) return;

  cvt_bf16<<<8192, 256, 0, stream>>>(x, x_bf);
  transpose_cvt<<<dim3(96, 64), 256, 0, stream>>>(Wqkv, wqkv_t, 2048, 3072);
  transpose_cvt<<<dim3(64, 64), 256, 0, stream>>>(Wproj, wproj_t, 2048, 2048);
  gemm_bt<3072, 2048, 1><<<dim3(32, 24), 256, 0, stream>>>(x_bf, wqkv_t, qkv_bf, nullptr);
  conv_rope_q<<<16384, 256, 0, stream>>>(qkv_bf, qw, cosT, sinT, q_bf);
  conv_kv<<<dim3(4096, 2), 256, 0, stream>>>(qkv_bf, kw, vw, cosT, sinT, k_bf, v_tmp);
  transpose_v16<<<dim3(16, 64, 2), 256, 0, stream>>>(v_tmp, v_t);
  attn_swin<<<1024, 256, 0, stream>>>(q_bf, k_bf, v_t, y_bf);
  gemm_bt<2048, 2048, 0><<<dim3(32, 16), 256, 0, stream>>>(y_bf, wproj_t, nullptr, out);
}